// Round 1
// baseline (179.697 us; speedup 1.0000x reference)
//
#include <hip/hip_runtime.h>
#include <hip/hip_bf16.h>

// out[b,o,hw] = sum_c W[o,c] * x[b,c,hw]
// x: (B, C, H, W) fp32 contiguous, C=256, H*W=3136 (784 float4, 16B-aligned).
// W: (C, C) fp32 (conv_weights[:, :, 0, 0]).
// Strategy: one block per (b, o). Threads cooperatively compact the nonzeros
// of row W[o,:] into LDS (general for any W; O(nnz) work per pixel), then
// stream the hw plane with coalesced float4 loads/stores.

#define C_CH 256
#define HW 3136
#define HW4 784  // HW / 4

__global__ __launch_bounds__(256) void channel_mix_sparse(
    const float* __restrict__ x,
    const float* __restrict__ w,   // (C_CH, C_CH), row-major; inner [1,1] dims are trivial
    float* __restrict__ out,
    int B) {
  __shared__ int   s_idx[C_CH];
  __shared__ float s_val[C_CH];
  __shared__ int   s_wavecnt[4];
  __shared__ int   s_nnz;

  const int tid = threadIdx.x;
  const int bo  = blockIdx.x;
  const int b   = bo >> 8;        // bo / 256
  const int o   = bo & 255;       // bo % 256

  // ---- compact nonzeros of W[o, :] into (s_idx, s_val), order-preserving ----
  const float wv = w[(size_t)o * C_CH + tid];
  const bool  nz = (wv != 0.0f);
  const unsigned long long mask = __ballot(nz);
  const int wave = tid >> 6;
  const int lane = tid & 63;
  if (lane == 0) s_wavecnt[wave] = __popcll(mask);
  __syncthreads();
  int woff = 0;
#pragma unroll
  for (int i = 0; i < 4; ++i) {
    if (i < wave) woff += s_wavecnt[i];
  }
  if (tid == 0) s_nnz = s_wavecnt[0] + s_wavecnt[1] + s_wavecnt[2] + s_wavecnt[3];
  const int pos = woff + __popcll(mask & ((1ull << lane) - 1ull));
  if (nz) { s_idx[pos] = tid; s_val[pos] = wv; }
  __syncthreads();

  const int nnz = s_nnz;

  // ---- stream the hw plane: coalesced float4 ----
  const float4* __restrict__ xb =
      (const float4*)(x + (size_t)b * C_CH * HW);
  float4* __restrict__ ob =
      (float4*)(out + ((size_t)b * C_CH + o) * HW);

  for (int p = tid; p < HW4; p += 256) {
    float4 acc = make_float4(0.f, 0.f, 0.f, 0.f);
    for (int k = 0; k < nnz; ++k) {
      const int   c = s_idx[k];
      const float v = s_val[k];
      const float4 xv = xb[(size_t)c * HW4 + p];
      acc.x += v * xv.x;
      acc.y += v * xv.y;
      acc.z += v * xv.z;
      acc.w += v * xv.w;
    }
    ob[p] = acc;
  }
}

extern "C" void kernel_launch(void* const* d_in, const int* in_sizes, int n_in,
                              void* d_out, int out_size, void* d_ws, size_t ws_size,
                              hipStream_t stream) {
  const float* x = (const float*)d_in[0];
  const float* w = (const float*)d_in[1];   // (256, 256, 1, 1) -> (256, 256)
  float* out = (float*)d_out;

  const int B = in_sizes[0] / (C_CH * HW);  // 32

  dim3 grid(B * C_CH);
  dim3 block(256);
  channel_mix_sparse<<<grid, block, 0, stream>>>(x, w, out, B);
}

// Round 2
// 172.506 us; speedup vs baseline: 1.0417x; 1.0417x over previous
//
#include <hip/hip_runtime.h>
#include <hip/hip_bf16.h>

// out[b,o,hw] = sum_c W[o,c] * x[b,c,hw]
// x: (B, C, H, W) fp32 contiguous, C=256, H*W=3136 (784 float4, 16B-aligned).
// W: (C, C) fp32 (conv_weights[:, :, 0, 0]).
// One block per (b, o). Prologue ballot-compacts the nonzeros of W[o,:] into
// LDS (general for any W; O(nnz) loads per pixel). Hot loop: k (nonzero)
// OUTSIDE, 4 independent float4 accumulators per thread so 4 HBM loads are
// in flight per thread before any waitcnt (MLP fix vs R1). Nontemporal
// loads/stores: pure streaming, keep L2 for the weight lists.

#define C_CH 256
#define HW 3136
#define HW4 784  // HW / 4

typedef float f4 __attribute__((ext_vector_type(4)));

__global__ __launch_bounds__(256) void channel_mix_sparse(
    const float* __restrict__ x,
    const float* __restrict__ w,   // (C_CH, C_CH) row-major
    float* __restrict__ out,
    int B) {
  __shared__ int   s_idx[C_CH];
  __shared__ float s_val[C_CH];
  __shared__ int   s_wavecnt[4];
  __shared__ int   s_nnz;

  const int tid = threadIdx.x;
  const int bo  = blockIdx.x;
  const int b   = bo >> 8;        // bo / 256
  const int o   = bo & 255;       // bo % 256

  // ---- compact nonzeros of W[o, :] into (s_idx, s_val), order-preserving ----
  const float wv = w[(size_t)o * C_CH + tid];
  const bool  nz = (wv != 0.0f);
  const unsigned long long mask = __ballot(nz);
  const int wave = tid >> 6;
  const int lane = tid & 63;
  if (lane == 0) s_wavecnt[wave] = __popcll(mask);
  __syncthreads();
  int woff = 0;
#pragma unroll
  for (int i = 0; i < 4; ++i) {
    if (i < wave) woff += s_wavecnt[i];
  }
  if (tid == 0) s_nnz = s_wavecnt[0] + s_wavecnt[1] + s_wavecnt[2] + s_wavecnt[3];
  const int pos = woff + __popcll(mask & ((1ull << lane) - 1ull));
  if (nz) { s_idx[pos] = tid; s_val[pos] = wv; }
  __syncthreads();

  const int nnz = s_nnz;

  const f4* __restrict__ xb = (const f4*)(x + (size_t)b * C_CH * HW);
  f4* __restrict__ ob = (f4*)(out + ((size_t)b * C_CH + o) * HW);

  // p-slots: tid, tid+256, tid+512 always < 784; tid+768 only for tid < 16.
  const int p0 = tid, p1 = tid + 256, p2 = tid + 512, p3 = tid + 768;
  const bool has3 = (p3 < HW4);

  f4 acc0 = (f4)0.f, acc1 = (f4)0.f, acc2 = (f4)0.f, acc3 = (f4)0.f;

  for (int k = 0; k < nnz; ++k) {
    const int   c = s_idx[k];
    const float v = s_val[k];
    const f4* __restrict__ src = xb + (size_t)c * HW4;
    // Issue all plane loads back-to-back -> 4 outstanding HBM loads/thread.
    f4 a0 = __builtin_nontemporal_load(src + p0);
    f4 a1 = __builtin_nontemporal_load(src + p1);
    f4 a2 = __builtin_nontemporal_load(src + p2);
    f4 a3 = has3 ? __builtin_nontemporal_load(src + p3) : (f4)0.f;
    acc0 += a0 * v;
    acc1 += a1 * v;
    acc2 += a2 * v;
    acc3 += a3 * v;
  }

  __builtin_nontemporal_store(acc0, ob + p0);
  __builtin_nontemporal_store(acc1, ob + p1);
  __builtin_nontemporal_store(acc2, ob + p2);
  if (has3) __builtin_nontemporal_store(acc3, ob + p3);
}

extern "C" void kernel_launch(void* const* d_in, const int* in_sizes, int n_in,
                              void* d_out, int out_size, void* d_ws, size_t ws_size,
                              hipStream_t stream) {
  const float* x = (const float*)d_in[0];
  const float* w = (const float*)d_in[1];   // (256, 256, 1, 1) -> (256, 256)
  float* out = (float*)d_out;

  const int B = in_sizes[0] / (C_CH * HW);  // 32

  dim3 grid(B * C_CH);
  dim3 block(256);
  channel_mix_sparse<<<grid, block, 0, stream>>>(x, w, out, B);
}